// Round 1
// baseline (836.641 us; speedup 1.0000x reference)
//
#include <hip/hip_runtime.h>
#include <hip/hip_fp16.h>

#define NN 10000
#define FF 32
#define PG 8      // pairs per group (interleaved layout)
#define NGRP 12   // 96 pairs / PG

__device__ __forceinline__ float h2f(unsigned short u){
  union { unsigned short s; _Float16 h; } c; c.s = u; return (float)c.h;
}
__device__ __forceinline__ unsigned short f2h(float f){
  union { unsigned short s; _Float16 h; } c; c.h = (_Float16)f; return c.s;
}

// ---- CSR build -------------------------------------------------------------
__global__ void k_count(const int* __restrict__ dst, int* __restrict__ cnt, int E){
  int e = blockIdx.x * 256 + threadIdx.x;
  if (e < E) atomicAdd(&cnt[dst[e]], 1);
}

__global__ __launch_bounds__(1024) void k_scan(const int* __restrict__ cnt,
                                               int* __restrict__ off,
                                               float* __restrict__ dinv){
  __shared__ int sd[1024];
  int tid = threadIdx.x;
  int run = 0;
  for (int base = 0; base < NN; base += 1024){
    int i = base + tid;
    int v = (i < NN) ? cnt[i] : 0;
    sd[tid] = v; __syncthreads();
    for (int o = 1; o < 1024; o <<= 1){
      int t = (tid >= o) ? sd[tid - o] : 0;
      __syncthreads();
      sd[tid] += t;
      __syncthreads();
    }
    if (i < NN){
      off[i]  = run + sd[tid] - v;                 // exclusive
      dinv[i] = rsqrtf((float)(v + 1));            // +1 self loop; deg>=1 always
    }
    int tot = sd[1023];
    __syncthreads();
    run += tot;
  }
  if (tid == 0) off[NN] = run;
}

__global__ void k_scatter(const int* __restrict__ ei, const int* __restrict__ off,
                          int* __restrict__ cur, const float* __restrict__ dinv,
                          int2* __restrict__ csr, int E){
  int e = blockIdx.x * 256 + threadIdx.x;
  if (e >= E) return;
  int s = ei[e], d = ei[E + e];
  int pos = off[d] + atomicAdd(&cur[d], 1);
  csr[pos] = make_int2(s, __float_as_int(dinv[s]));  // (src, dinv[src])
}

// ---- W12 = W1@W2 (33x32), bb = b1@W2 (32) ---------------------------------
__global__ void k_w12(const float* __restrict__ W1, const float* __restrict__ W2,
                      const float* __restrict__ b1, float* __restrict__ W12,
                      float* __restrict__ bb){
  for (int idx = threadIdx.x; idx < 33 * 32; idx += 256){
    int k = idx >> 5, j = idx & 31;
    float s = 0.f;
    for (int m = 0; m < 64; ++m) s += W1[k * 64 + m] * W2[m * 32 + j];
    W12[idx] = s;
  }
  if (threadIdx.x < 32){
    int j = threadIdx.x;
    float s = 0.f;
    for (int m = 0; m < 64; ++m) s += b1[m] * W2[m * 32 + j];
    bb[j] = s;
  }
}

// ---- s[n] = rowsum(A) ------------------------------------------------------
__global__ void k_srow(const int* __restrict__ off, const int2* __restrict__ csr,
                       const float* __restrict__ dinv, float* __restrict__ srow){
  int n = blockIdx.x * 256 + threadIdx.x;
  if (n >= NN) return;
  float a = dinv[n];
  int e0 = off[n], e1 = off[n + 1];
  for (int j = e0; j < e1; ++j) a += __int_as_float(csr[j].y);
  srow[n] = dinv[n] * a;
}

// ---- GEMM1: hw[g][n][p][f] = x[pg,n,:]@W12[:32] + mask[pg]*W12[32]  (fp16) -
// thread: q = feature quad (8), p = pair (8), wave = node. W12 slice in regs.
__global__ __launch_bounds__(256, 2) void k_gemm1(const float* __restrict__ x,
    const float* __restrict__ mask, const float* __restrict__ W12,
    ushort4* __restrict__ hw, int pair_base){
  int t = threadIdx.x;
  int q = t & 7, p = (t >> 3) & 7, w = t >> 6;
  int pg = pair_base + blockIdx.y * PG + p;
  const float4* wp = (const float4*)W12;
  float4 wr[33];
  #pragma unroll
  for (int k = 0; k < 33; ++k) wr[k] = wp[k * 8 + q];
  float mv = mask[pg];
  float4 mterm = make_float4(mv * wr[32].x, mv * wr[32].y, mv * wr[32].z, mv * wr[32].w);
  const float* xbase = x + (size_t)pg * NN * FF;
  ushort4* hwg = hw + (size_t)blockIdx.y * (NN * 64);
  for (int it = 0; it < 16; ++it){
    int n = blockIdx.x * 64 + it * 4 + w;
    if (n < NN){
      const float4* xp = (const float4*)(xbase + (size_t)n * FF);
      float xr[32];
      #pragma unroll
      for (int i = 0; i < 8; ++i){
        float4 v = xp[i];
        xr[4*i] = v.x; xr[4*i+1] = v.y; xr[4*i+2] = v.z; xr[4*i+3] = v.w;
      }
      float4 acc = mterm;
      #pragma unroll
      for (int k = 0; k < 32; ++k){
        acc.x += xr[k] * wr[k].x; acc.y += xr[k] * wr[k].y;
        acc.z += xr[k] * wr[k].z; acc.w += xr[k] * wr[k].w;
      }
      ushort4 us;
      us.x = f2h(acc.x); us.y = f2h(acc.y); us.z = f2h(acc.z); us.w = f2h(acc.w);
      hwg[(size_t)n * 64 + (t & 63)] = us;   // contiguous 512B per wave-node
    }
  }
}

// ---- agg layer 1: t1 = A·hw (fp16 -> fp16), same interleaved layout --------
__global__ __launch_bounds__(256, 4) void k_agg1(const int* __restrict__ off,
    const int2* __restrict__ csr, const float* __restrict__ dinv,
    const ushort4* __restrict__ V, ushort4* __restrict__ T){
  int l = threadIdx.x & 63, w = threadIdx.x >> 6;
  const ushort4* Vg = V + (size_t)blockIdx.y * (NN * 64);
  ushort4*       Tg = T + (size_t)blockIdx.y * (NN * 64);
  for (int it = 0; it < 4; ++it){
    int n = blockIdx.x * 16 + w * 4 + it;          // 625*16 == NN exactly
    float din = dinv[n];
    ushort4 sv = Vg[(size_t)n * 64 + l];
    float4 acc = make_float4(din * h2f(sv.x), din * h2f(sv.y),
                             din * h2f(sv.z), din * h2f(sv.w));
    int e0 = off[n], e1 = off[n + 1], jm = e1 - 1;
    for (int j = e0; j < e1; j += 4){
      int j1 = (j+1 > jm) ? jm : j+1;
      int j2 = (j+2 > jm) ? jm : j+2;
      int j3 = (j+3 > jm) ? jm : j+3;
      int2 c0 = csr[j], c1 = csr[j1], c2 = csr[j2], c3 = csr[j3];
      float w0 = __int_as_float(c0.y);
      float w1 = (j+1 <= jm) ? __int_as_float(c1.y) : 0.f;
      float w2 = (j+2 <= jm) ? __int_as_float(c2.y) : 0.f;
      float w3 = (j+3 <= jm) ? __int_as_float(c3.y) : 0.f;
      ushort4 r0 = Vg[(size_t)c0.x * 64 + l];
      ushort4 r1 = Vg[(size_t)c1.x * 64 + l];
      ushort4 r2 = Vg[(size_t)c2.x * 64 + l];
      ushort4 r3 = Vg[(size_t)c3.x * 64 + l];
      acc.x += w0*h2f(r0.x) + w1*h2f(r1.x) + w2*h2f(r2.x) + w3*h2f(r3.x);
      acc.y += w0*h2f(r0.y) + w1*h2f(r1.y) + w2*h2f(r2.y) + w3*h2f(r3.y);
      acc.z += w0*h2f(r0.z) + w1*h2f(r1.z) + w2*h2f(r2.z) + w3*h2f(r3.z);
      acc.w += w0*h2f(r0.w) + w1*h2f(r1.w) + w2*h2f(r2.w) + w3*h2f(r3.w);
    }
    ushort4 us;
    us.x = f2h(din * acc.x); us.y = f2h(din * acc.y);
    us.z = f2h(din * acc.z); us.w = f2h(din * acc.w);
    Tg[(size_t)n * 64 + l] = us;
  }
}

// ---- agg layer 2 + epilogue: out = tanh(A·t1 + s[n]*bb + b2) (fp32) --------
__global__ __launch_bounds__(256, 4) void k_agg2(const int* __restrict__ off,
    const int2* __restrict__ csr, const float* __restrict__ dinv,
    const float* __restrict__ srow, const float* __restrict__ bb,
    const float* __restrict__ b2, const ushort4* __restrict__ V,
    float* __restrict__ out, int pair_base){
  int l = threadIdx.x & 63, w = threadIdx.x >> 6;
  int p = l >> 3, q = l & 7;
  const ushort4* Vg = V + (size_t)blockIdx.y * (NN * 64);
  int pg = pair_base + blockIdx.y * PG + p;
  float4 bbq = ((const float4*)bb)[q];
  float4 b2q = ((const float4*)b2)[q];
  float* outp = out + (size_t)pg * (NN * FF);
  for (int it = 0; it < 4; ++it){
    int n = blockIdx.x * 16 + w * 4 + it;
    float din = dinv[n];
    ushort4 sv = Vg[(size_t)n * 64 + l];
    float4 acc = make_float4(din * h2f(sv.x), din * h2f(sv.y),
                             din * h2f(sv.z), din * h2f(sv.w));
    int e0 = off[n], e1 = off[n + 1], jm = e1 - 1;
    for (int j = e0; j < e1; j += 4){
      int j1 = (j+1 > jm) ? jm : j+1;
      int j2 = (j+2 > jm) ? jm : j+2;
      int j3 = (j+3 > jm) ? jm : j+3;
      int2 c0 = csr[j], c1 = csr[j1], c2 = csr[j2], c3 = csr[j3];
      float w0 = __int_as_float(c0.y);
      float w1 = (j+1 <= jm) ? __int_as_float(c1.y) : 0.f;
      float w2 = (j+2 <= jm) ? __int_as_float(c2.y) : 0.f;
      float w3 = (j+3 <= jm) ? __int_as_float(c3.y) : 0.f;
      ushort4 r0 = Vg[(size_t)c0.x * 64 + l];
      ushort4 r1 = Vg[(size_t)c1.x * 64 + l];
      ushort4 r2 = Vg[(size_t)c2.x * 64 + l];
      ushort4 r3 = Vg[(size_t)c3.x * 64 + l];
      acc.x += w0*h2f(r0.x) + w1*h2f(r1.x) + w2*h2f(r2.x) + w3*h2f(r3.x);
      acc.y += w0*h2f(r0.y) + w1*h2f(r1.y) + w2*h2f(r2.y) + w3*h2f(r3.y);
      acc.z += w0*h2f(r0.z) + w1*h2f(r1.z) + w2*h2f(r2.z) + w3*h2f(r3.z);
      acc.w += w0*h2f(r0.w) + w1*h2f(r1.w) + w2*h2f(r2.w) + w3*h2f(r3.w);
    }
    float sr = srow[n];
    float4 o;
    o.x = tanhf(din * acc.x + sr * bbq.x + b2q.x);
    o.y = tanhf(din * acc.y + sr * bbq.y + b2q.y);
    o.z = tanhf(din * acc.z + sr * bbq.z + b2q.z);
    o.w = tanhf(din * acc.w + sr * bbq.w + b2q.w);
    ((float4*)(outp + (size_t)n * FF))[q] = o;
  }
}

extern "C" void kernel_launch(void* const* d_in, const int* in_sizes, int n_in,
                              void* d_out, int out_size, void* d_ws, size_t ws_size,
                              hipStream_t stream){
  const float* x    = (const float*)d_in[0];
  const float* mask = (const float*)d_in[1];
  const int*   ei   = (const int*)d_in[2];
  const float* W1   = (const float*)d_in[3];
  const float* b1   = (const float*)d_in[4];
  const float* W2   = (const float*)d_in[5];
  const float* b2   = (const float*)d_in[6];
  float* out = (float*)d_out;
  const int E = in_sizes[2] / 2;   // 320000

  // workspace carve (256B aligned regions)
  char* wsp = (char*)d_ws;
  auto alloc = [&](size_t bytes) -> char* {
    char* p = wsp; wsp += (bytes + 255) & ~(size_t)255; return p;
  };
  int*   cnt  = (int*)  alloc((size_t)NN * 4);
  int*   off  = (int*)  alloc((size_t)(NN + 1) * 4);
  int*   cur  = (int*)  alloc((size_t)NN * 4);
  float* dinv = (float*)alloc((size_t)NN * 4);
  float* srow = (float*)alloc((size_t)NN * 4);
  float* W12  = (float*)alloc(33 * 32 * 4);
  float* bbv  = (float*)alloc(32 * 4);
  int2*  csr  = (int2*) alloc((size_t)E * 8);
  size_t used = (size_t)(wsp - (char*)d_ws);
  const size_t per_group = (size_t)NN * 256 * 2;   // fp16 [n][8][32] = 5.12MB
  int gc = 1;
  if (ws_size > used + 2 * per_group){
    gc = (int)((ws_size - used) / (2 * per_group));
    if (gc > NGRP) gc = NGRP;
    if (gc < 1) gc = 1;
  }
  ushort4* hw = (ushort4*)alloc((size_t)gc * per_group);
  ushort4* t1 = (ushort4*)alloc((size_t)gc * per_group);

  hipMemsetAsync(cnt, 0, (size_t)NN * 4, stream);
  hipMemsetAsync(cur, 0, (size_t)NN * 4, stream);
  k_count  <<<(E + 255) / 256, 256, 0, stream>>>(ei + E, cnt, E);
  k_scan   <<<1, 1024, 0, stream>>>(cnt, off, dinv);
  k_scatter<<<(E + 255) / 256, 256, 0, stream>>>(ei, off, cur, dinv, csr, E);
  k_w12    <<<1, 256, 0, stream>>>(W1, W2, b1, W12, bbv);
  k_srow   <<<(NN + 255) / 256, 256, 0, stream>>>(off, csr, dinv, srow);

  for (int gb = 0; gb < NGRP; gb += gc){
    int g = (NGRP - gb < gc) ? (NGRP - gb) : gc;
    int pair_base = gb * PG;
    k_gemm1<<<dim3(157, g), 256, 0, stream>>>(x, mask, W12, hw, pair_base);
    k_agg1 <<<dim3(625, g), 256, 0, stream>>>(off, csr, dinv, hw, t1);
    k_agg2 <<<dim3(625, g), 256, 0, stream>>>(off, csr, dinv, srow, bbv, b2, t1, out, pair_base);
  }
}

// Round 2
// 765.210 us; speedup vs baseline: 1.0933x; 1.0933x over previous
//
#include <hip/hip_runtime.h>
#include <hip/hip_fp16.h>

#define NN 10000
#define FF 32
#define PG 4      // pairs per group
#define NGRP 24   // 96 pairs / PG

__device__ __forceinline__ float h2f(unsigned short u){
  union { unsigned short s; _Float16 h; } c; c.s = u; return (float)c.h;
}
__device__ __forceinline__ unsigned short f2h(float f){
  union { unsigned short s; _Float16 h; } c; c.h = (_Float16)f; return c.s;
}

// ---- CSR build -------------------------------------------------------------
__global__ void k_count(const int* __restrict__ dst, int* __restrict__ cnt, int E){
  int e = blockIdx.x * 256 + threadIdx.x;
  if (e < E) atomicAdd(&cnt[dst[e]], 1);
}

__global__ __launch_bounds__(1024) void k_scan(const int* __restrict__ cnt,
                                               int* __restrict__ off,
                                               float* __restrict__ dinv){
  __shared__ int sd[1024];
  int tid = threadIdx.x;
  int run = 0;
  for (int base = 0; base < NN; base += 1024){
    int i = base + tid;
    int v = (i < NN) ? cnt[i] : 0;
    sd[tid] = v; __syncthreads();
    for (int o = 1; o < 1024; o <<= 1){
      int t = (tid >= o) ? sd[tid - o] : 0;
      __syncthreads();
      sd[tid] += t;
      __syncthreads();
    }
    if (i < NN){
      off[i]  = run + sd[tid] - v;                 // exclusive
      dinv[i] = rsqrtf((float)(v + 1));            // +1 self loop
    }
    int tot = sd[1023];
    __syncthreads();
    run += tot;
  }
  if (tid == 0) off[NN] = run;
}

// csr entry: low16 = src node id, high16 = fp16(dinv[src])
__global__ void k_scatter(const int* __restrict__ ei, const int* __restrict__ off,
                          int* __restrict__ cur, const float* __restrict__ dinv,
                          unsigned int* __restrict__ csr, int E){
  int e = blockIdx.x * 256 + threadIdx.x;
  if (e >= E) return;
  int s = ei[e], d = ei[E + e];
  int pos = off[d] + atomicAdd(&cur[d], 1);
  csr[pos] = (unsigned int)s | ((unsigned int)f2h(dinv[s]) << 16);
}

// ---- W12 = W1@W2 (33x32), bb = b1@W2 (32) ---------------------------------
__global__ void k_w12(const float* __restrict__ W1, const float* __restrict__ W2,
                      const float* __restrict__ b1, float* __restrict__ W12,
                      float* __restrict__ bb){
  for (int idx = threadIdx.x; idx < 33 * 32; idx += 256){
    int k = idx >> 5, j = idx & 31;
    float s = 0.f;
    for (int m = 0; m < 64; ++m) s += W1[k * 64 + m] * W2[m * 32 + j];
    W12[idx] = s;
  }
  if (threadIdx.x < 32){
    int j = threadIdx.x;
    float s = 0.f;
    for (int m = 0; m < 64; ++m) s += b1[m] * W2[m * 32 + j];
    bb[j] = s;
  }
}

// ---- s[n] = rowsum(A) ------------------------------------------------------
__global__ void k_srow(const int* __restrict__ off, const unsigned int* __restrict__ csr,
                       const float* __restrict__ dinv, float* __restrict__ srow){
  int n = blockIdx.x * 256 + threadIdx.x;
  if (n >= NN) return;
  float a = dinv[n];
  int e0 = off[n], e1 = off[n + 1];
  for (int j = e0; j < e1; ++j) a += h2f((unsigned short)(csr[j] >> 16));
  srow[n] = dinv[n] * a;
}

// ---- GEMM1: hw[g][n][p=4][f=32] fp16 = x@W12[:32] + mask*W12[32] -----------
// thread: q = feature quad (8), p = pair (4), nl = node lane (8). Prefetched.
__global__ __launch_bounds__(256) void k_gemm1(const float* __restrict__ x,
    const float* __restrict__ mask, const float* __restrict__ W12,
    ushort4* __restrict__ hw){
  int t = threadIdx.x;
  int q = t & 7, p = (t >> 3) & 3, nl = t >> 5;
  int grp = blockIdx.y;
  int pg = grp * PG + p;
  const float4* wp = (const float4*)W12;
  float4 wr[33];
  #pragma unroll
  for (int k = 0; k < 33; ++k) wr[k] = wp[k * 8 + q];
  float mv = mask[pg];
  float4 mterm = make_float4(mv * wr[32].x, mv * wr[32].y, mv * wr[32].z, mv * wr[32].w);
  const float* xbase = x + (size_t)pg * NN * FF;
  ushort4* hwg = hw + (size_t)grp * (NN * 32);
  int n = blockIdx.x * 128 + nl;
  float4 xr[8];
  if (n < NN){
    const float4* xp = (const float4*)(xbase + (size_t)n * FF);
    #pragma unroll
    for (int i = 0; i < 8; ++i) xr[i] = xp[i];
  }
  for (int it = 0; it < 16; ++it){
    int nn = blockIdx.x * 128 + (it + 1) * 8 + nl;
    float4 xn[8];
    if (it < 15 && nn < NN){
      const float4* xp2 = (const float4*)(xbase + (size_t)nn * FF);
      #pragma unroll
      for (int i = 0; i < 8; ++i) xn[i] = xp2[i];
    }
    if (n < NN){
      float4 acc = mterm;
      #pragma unroll
      for (int i = 0; i < 8; ++i){
        float4 v = xr[i];
        acc.x += v.x*wr[4*i].x + v.y*wr[4*i+1].x + v.z*wr[4*i+2].x + v.w*wr[4*i+3].x;
        acc.y += v.x*wr[4*i].y + v.y*wr[4*i+1].y + v.z*wr[4*i+2].y + v.w*wr[4*i+3].y;
        acc.z += v.x*wr[4*i].z + v.y*wr[4*i+1].z + v.z*wr[4*i+2].z + v.w*wr[4*i+3].z;
        acc.w += v.x*wr[4*i].w + v.y*wr[4*i+1].w + v.z*wr[4*i+2].w + v.w*wr[4*i+3].w;
      }
      ushort4 us;
      us.x = f2h(acc.x); us.y = f2h(acc.y); us.z = f2h(acc.z); us.w = f2h(acc.w);
      hwg[(size_t)n * 32 + (p << 3) + q] = us;   // [n][p][f] row = 256B/wave
    }
    #pragma unroll
    for (int i = 0; i < 8; ++i) xr[i] = xn[i];
    n = nn;
  }
}

// ---- block->group mapping: pin each group to one XCD (blockIdx%8 heuristic)
__device__ __forceinline__ void map_block(int bx, int& grp, int& chunk){
  int r  = bx / 5000;       // 0..2
  int w8 = bx % 5000;
  grp   = r * 8 + (w8 & 7); // all blocks of grp share bx%8 -> same XCD
  chunk = w8 >> 3;          // 0..624
}

// ---- agg layer 1: t1 = A*hw (fp16 -> fp16), row = 128 fp16 = 64 uint -------
__global__ __launch_bounds__(256) void k_agg1(const int* __restrict__ off,
    const unsigned int* __restrict__ csr, const float* __restrict__ dinv,
    const unsigned int* __restrict__ V, unsigned int* __restrict__ T){
  int grp, chunk; map_block(blockIdx.x, grp, chunk);
  int l = threadIdx.x & 63, w = threadIdx.x >> 6;
  const unsigned int* Vg = V + (size_t)grp * (NN * 64);
  unsigned int*       Tg = T + (size_t)grp * (NN * 64);
  for (int it = 0; it < 4; ++it){
    int n = chunk * 16 + w * 4 + it;
    float din = dinv[n];
    unsigned int sv = Vg[((size_t)n << 6) + l];
    float2 acc;
    acc.x = din * h2f((unsigned short)(sv & 0xffff));
    acc.y = din * h2f((unsigned short)(sv >> 16));
    int e0 = off[n], e1 = off[n + 1], jm = e1 - 1;
    for (int j = e0; j < e1; j += 4){
      int j1 = (j+1 > jm) ? jm : j+1;
      int j2 = (j+2 > jm) ? jm : j+2;
      int j3 = (j+3 > jm) ? jm : j+3;
      unsigned int c0 = csr[j], c1 = csr[j1], c2 = csr[j2], c3 = csr[j3];
      float w0 = h2f((unsigned short)(c0 >> 16));
      float w1 = (j+1 <= jm) ? h2f((unsigned short)(c1 >> 16)) : 0.f;
      float w2 = (j+2 <= jm) ? h2f((unsigned short)(c2 >> 16)) : 0.f;
      float w3 = (j+3 <= jm) ? h2f((unsigned short)(c3 >> 16)) : 0.f;
      unsigned int r0 = Vg[((c0 & 0xffffu) << 6) + l];
      unsigned int r1 = Vg[((c1 & 0xffffu) << 6) + l];
      unsigned int r2 = Vg[((c2 & 0xffffu) << 6) + l];
      unsigned int r3 = Vg[((c3 & 0xffffu) << 6) + l];
      acc.x += w0*h2f((unsigned short)(r0 & 0xffff)) + w1*h2f((unsigned short)(r1 & 0xffff))
             + w2*h2f((unsigned short)(r2 & 0xffff)) + w3*h2f((unsigned short)(r3 & 0xffff));
      acc.y += w0*h2f((unsigned short)(r0 >> 16)) + w1*h2f((unsigned short)(r1 >> 16))
             + w2*h2f((unsigned short)(r2 >> 16)) + w3*h2f((unsigned short)(r3 >> 16));
    }
    unsigned int us = (unsigned int)f2h(din * acc.x)
                    | ((unsigned int)f2h(din * acc.y) << 16);
    Tg[((size_t)n << 6) + l] = us;
  }
}

// ---- agg layer 2 + epilogue: out = tanh(A*t1 + srow*bb + b2) fp32 ----------
__global__ __launch_bounds__(256) void k_agg2(const int* __restrict__ off,
    const unsigned int* __restrict__ csr, const float* __restrict__ dinv,
    const float* __restrict__ srow, const float* __restrict__ bb,
    const float* __restrict__ b2, const unsigned int* __restrict__ V,
    float* __restrict__ out){
  int grp, chunk; map_block(blockIdx.x, grp, chunk);
  int l = threadIdx.x & 63, w = threadIdx.x >> 6;
  int p = l >> 4, fi = l & 15;           // lane covers feats 2*fi, 2*fi+1 of pair p
  const unsigned int* Vg = V + (size_t)grp * (NN * 64);
  int pg = grp * PG + p;
  float2 bbq = ((const float2*)bb)[fi];
  float2 b2q = ((const float2*)b2)[fi];
  float* outp = out + (size_t)pg * (NN * FF);
  for (int it = 0; it < 4; ++it){
    int n = chunk * 16 + w * 4 + it;
    float din = dinv[n];
    unsigned int sv = Vg[((size_t)n << 6) + l];
    float2 acc;
    acc.x = din * h2f((unsigned short)(sv & 0xffff));
    acc.y = din * h2f((unsigned short)(sv >> 16));
    int e0 = off[n], e1 = off[n + 1], jm = e1 - 1;
    for (int j = e0; j < e1; j += 4){
      int j1 = (j+1 > jm) ? jm : j+1;
      int j2 = (j+2 > jm) ? jm : j+2;
      int j3 = (j+3 > jm) ? jm : j+3;
      unsigned int c0 = csr[j], c1 = csr[j1], c2 = csr[j2], c3 = csr[j3];
      float w0 = h2f((unsigned short)(c0 >> 16));
      float w1 = (j+1 <= jm) ? h2f((unsigned short)(c1 >> 16)) : 0.f;
      float w2 = (j+2 <= jm) ? h2f((unsigned short)(c2 >> 16)) : 0.f;
      float w3 = (j+3 <= jm) ? h2f((unsigned short)(c3 >> 16)) : 0.f;
      unsigned int r0 = Vg[((c0 & 0xffffu) << 6) + l];
      unsigned int r1 = Vg[((c1 & 0xffffu) << 6) + l];
      unsigned int r2 = Vg[((c2 & 0xffffu) << 6) + l];
      unsigned int r3 = Vg[((c3 & 0xffffu) << 6) + l];
      acc.x += w0*h2f((unsigned short)(r0 & 0xffff)) + w1*h2f((unsigned short)(r1 & 0xffff))
             + w2*h2f((unsigned short)(r2 & 0xffff)) + w3*h2f((unsigned short)(r3 & 0xffff));
      acc.y += w0*h2f((unsigned short)(r0 >> 16)) + w1*h2f((unsigned short)(r1 >> 16))
             + w2*h2f((unsigned short)(r2 >> 16)) + w3*h2f((unsigned short)(r3 >> 16));
    }
    float sr = srow[n];
    float2 o;
    o.x = tanhf(din * acc.x + sr * bbq.x + b2q.x);
    o.y = tanhf(din * acc.y + sr * bbq.y + b2q.y);
    ((float2*)(outp + (size_t)n * FF))[fi] = o;
  }
}

extern "C" void kernel_launch(void* const* d_in, const int* in_sizes, int n_in,
                              void* d_out, int out_size, void* d_ws, size_t ws_size,
                              hipStream_t stream){
  const float* x    = (const float*)d_in[0];
  const float* mask = (const float*)d_in[1];
  const int*   ei   = (const int*)d_in[2];
  const float* W1   = (const float*)d_in[3];
  const float* b1   = (const float*)d_in[4];
  const float* W2   = (const float*)d_in[5];
  const float* b2   = (const float*)d_in[6];
  float* out = (float*)d_out;
  const int E = in_sizes[2] / 2;   // 320000

  char* wsp = (char*)d_ws;
  auto alloc = [&](size_t bytes) -> char* {
    char* p = wsp; wsp += (bytes + 255) & ~(size_t)255; return p;
  };
  int*   cnt  = (int*)  alloc((size_t)NN * 4);
  int*   off  = (int*)  alloc((size_t)(NN + 1) * 4);
  int*   cur  = (int*)  alloc((size_t)NN * 4);
  float* dinv = (float*)alloc((size_t)NN * 4);
  float* srow = (float*)alloc((size_t)NN * 4);
  float* W12  = (float*)alloc(33 * 32 * 4);
  float* bbv  = (float*)alloc(32 * 4);
  unsigned int* csr = (unsigned int*)alloc((size_t)E * 4);
  const size_t per_group = (size_t)NN * 64 * 4;    // [n][4p][32f] fp16 = 2.56MB
  unsigned int* hw = (unsigned int*)alloc((size_t)NGRP * per_group);
  unsigned int* t1 = (unsigned int*)alloc((size_t)NGRP * per_group);

  hipMemsetAsync(cnt, 0, (size_t)NN * 4, stream);
  hipMemsetAsync(cur, 0, (size_t)NN * 4, stream);
  k_count  <<<(E + 255) / 256, 256, 0, stream>>>(ei + E, cnt, E);
  k_scan   <<<1, 1024, 0, stream>>>(cnt, off, dinv);
  k_scatter<<<(E + 255) / 256, 256, 0, stream>>>(ei, off, cur, dinv, csr, E);
  k_w12    <<<1, 256, 0, stream>>>(W1, W2, b1, W12, bbv);
  k_srow   <<<(NN + 255) / 256, 256, 0, stream>>>(off, csr, dinv, srow);

  k_gemm1<<<dim3(79, NGRP), 256, 0, stream>>>(x, mask, W12, (ushort4*)hw);
  k_agg1 <<<15000, 256, 0, stream>>>(off, csr, dinv, hw, t1);
  k_agg2 <<<15000, 256, 0, stream>>>(off, csr, dinv, srow, bbv, b2, t1, out);
}

// Round 3
// 633.827 us; speedup vs baseline: 1.3200x; 1.2073x over previous
//
#include <hip/hip_runtime.h>
#include <hip/hip_fp16.h>

#define NN 10000
#define FF 32
#define PG 4      // pairs per group
#define NGRP 24   // 96 pairs / PG

__device__ __forceinline__ float h2f(unsigned short u){
  union { unsigned short s; _Float16 h; } c; c.s = u; return (float)c.h;
}
__device__ __forceinline__ unsigned short f2h(float f){
  union { unsigned short s; _Float16 h; } c; c.h = (_Float16)f; return c.s;
}

// ---- CSR build -------------------------------------------------------------
__global__ void k_count(const int* __restrict__ dst, int* __restrict__ cnt, int E){
  int e = blockIdx.x * 256 + threadIdx.x;
  if (e < E) atomicAdd(&cnt[dst[e]], 1);
}

// exclusive scan of PADDED counts (pad to multiple of 4); dinv from real count
__global__ __launch_bounds__(1024) void k_scan(const int* __restrict__ cnt,
                                               int* __restrict__ off,
                                               float* __restrict__ dinv){
  __shared__ int wsum[16];
  __shared__ int carry;
  int tid = threadIdx.x, lane = tid & 63, wv = tid >> 6;
  if (tid == 0) carry = 0;
  __syncthreads();
  for (int base = 0; base < NN; base += 1024){
    int i = base + tid;
    int c = (i < NN) ? cnt[i] : 0;
    int v = (c + 3) & ~3;                      // padded degree
    int s = v;
    #pragma unroll
    for (int o = 1; o < 64; o <<= 1){
      int t = __shfl_up(s, o, 64);
      if (lane >= o) s += t;
    }
    if (lane == 63) wsum[wv] = s;
    __syncthreads();
    if (tid == 0){
      int a = carry;
      #pragma unroll
      for (int k = 0; k < 16; ++k){ int t = wsum[k]; wsum[k] = a; a += t; }
      carry = a;
    }
    __syncthreads();
    if (i < NN){
      off[i]  = wsum[wv] + s - v;              // exclusive padded offset
      dinv[i] = rsqrtf((float)(c + 1));        // real degree + self loop
    }
    __syncthreads();
  }
  if (tid == 0) off[NN] = carry;
}

// csr entry: {row byte offset (src*256), fp32 weight dinv[src]}
// pad holes (memset 0) read row 0 with weight 0.0 -> harmless.
__global__ void k_scatter(const int* __restrict__ ei, const int* __restrict__ off,
                          int* __restrict__ cur, const float* __restrict__ dinv,
                          int2* __restrict__ csr, int E){
  int e = blockIdx.x * 256 + threadIdx.x;
  if (e >= E) return;
  int s = ei[e], d = ei[E + e];
  int pos = off[d] + atomicAdd(&cur[d], 1);
  csr[pos] = make_int2(s << 8, __float_as_int(dinv[s]));
}

// ---- W12 = W1@W2 (33x32), bb = b1@W2 (32) ---------------------------------
__global__ void k_w12(const float* __restrict__ W1, const float* __restrict__ W2,
                      const float* __restrict__ b1, float* __restrict__ W12,
                      float* __restrict__ bb){
  for (int idx = threadIdx.x; idx < 33 * 32; idx += 256){
    int k = idx >> 5, j = idx & 31;
    float s = 0.f;
    for (int m = 0; m < 64; ++m) s += W1[k * 64 + m] * W2[m * 32 + j];
    W12[idx] = s;
  }
  if (threadIdx.x < 32){
    int j = threadIdx.x;
    float s = 0.f;
    for (int m = 0; m < 64; ++m) s += b1[m] * W2[m * 32 + j];
    bb[j] = s;
  }
}

// ---- s[n] = rowsum(A) ------------------------------------------------------
__global__ void k_srow(const int* __restrict__ off, const int2* __restrict__ csr,
                       const float* __restrict__ dinv, float* __restrict__ srow){
  int n = blockIdx.x * 256 + threadIdx.x;
  if (n >= NN) return;
  float a = dinv[n];
  int e0 = off[n], e1 = off[n + 1];
  for (int j = e0; j < e1; ++j) a += __int_as_float(csr[j].y);  // pads add 0
  srow[n] = dinv[n] * a;
}

// ---- GEMM1: hw[g][n][p=4][f=32] fp16 = x@W12[:32] + mask*W12[32] -----------
__global__ __launch_bounds__(256) void k_gemm1(const float* __restrict__ x,
    const float* __restrict__ mask, const float* __restrict__ W12,
    ushort4* __restrict__ hw){
  int t = threadIdx.x;
  int q = t & 7, p = (t >> 3) & 3, nl = t >> 5;
  int grp = blockIdx.y;
  int pg = grp * PG + p;
  const float4* wp = (const float4*)W12;
  float4 wr[33];
  #pragma unroll
  for (int k = 0; k < 33; ++k) wr[k] = wp[k * 8 + q];
  float mv = mask[pg];
  float4 mterm = make_float4(mv * wr[32].x, mv * wr[32].y, mv * wr[32].z, mv * wr[32].w);
  const float* xbase = x + (size_t)pg * NN * FF;
  ushort4* hwg = hw + (size_t)grp * (NN * 32);
  int n = blockIdx.x * 128 + nl;
  float4 xr[8];
  if (n < NN){
    const float4* xp = (const float4*)(xbase + (size_t)n * FF);
    #pragma unroll
    for (int i = 0; i < 8; ++i) xr[i] = xp[i];
  }
  for (int it = 0; it < 16; ++it){
    int nn = blockIdx.x * 128 + (it + 1) * 8 + nl;
    float4 xn[8];
    if (it < 15 && nn < NN){
      const float4* xp2 = (const float4*)(xbase + (size_t)nn * FF);
      #pragma unroll
      for (int i = 0; i < 8; ++i) xn[i] = xp2[i];
    }
    if (n < NN){
      float4 acc = mterm;
      #pragma unroll
      for (int i = 0; i < 8; ++i){
        float4 v = xr[i];
        acc.x += v.x*wr[4*i].x + v.y*wr[4*i+1].x + v.z*wr[4*i+2].x + v.w*wr[4*i+3].x;
        acc.y += v.x*wr[4*i].y + v.y*wr[4*i+1].y + v.z*wr[4*i+2].y + v.w*wr[4*i+3].y;
        acc.z += v.x*wr[4*i].z + v.y*wr[4*i+1].z + v.z*wr[4*i+2].z + v.w*wr[4*i+3].z;
        acc.w += v.x*wr[4*i].w + v.y*wr[4*i+1].w + v.z*wr[4*i+2].w + v.w*wr[4*i+3].w;
      }
      ushort4 us;
      us.x = f2h(acc.x); us.y = f2h(acc.y); us.z = f2h(acc.z); us.w = f2h(acc.w);
      hwg[(size_t)n * 32 + (p << 3) + q] = us;
    }
    #pragma unroll
    for (int i = 0; i < 8; ++i) xr[i] = xn[i];
    n = nn;
  }
}

// ---- block->group mapping: pin each group to one XCD (blockIdx%8) ----------
__device__ __forceinline__ void map_block(int bx, int& grp, int& chunk){
  int r  = bx / 5000;       // 0..2
  int w8 = bx % 5000;
  grp   = r * 8 + (w8 & 7);
  chunk = w8 >> 3;          // 0..624
}

#define RFL(v) __builtin_amdgcn_readfirstlane(v)

__device__ __forceinline__ void edge4(const char* Vb, int loff,
    int o0, float w0, int o1, float w1, int o2, float w2, int o3, float w3,
    float& ax, float& ay){
  unsigned r0 = *(const unsigned*)(Vb + o0 + loff);
  unsigned r1 = *(const unsigned*)(Vb + o1 + loff);
  unsigned r2 = *(const unsigned*)(Vb + o2 + loff);
  unsigned r3 = *(const unsigned*)(Vb + o3 + loff);
  union { unsigned u; _Float16 h[2]; } u0, u1, u2, u3;
  u0.u = r0; u1.u = r1; u2.u = r2; u3.u = r3;
  ax += w0*(float)u0.h[0] + w1*(float)u1.h[0] + w2*(float)u2.h[0] + w3*(float)u3.h[0];
  ay += w0*(float)u0.h[1] + w1*(float)u1.h[1] + w2*(float)u2.h[1] + w3*(float)u3.h[1];
}

// ---- agg layer 1: t1 = A*hw (fp16 rows, fp32 accum) ------------------------
__global__ __launch_bounds__(256) void k_agg1(const int* __restrict__ off,
    const int2* __restrict__ csr, const float* __restrict__ dinv,
    const unsigned int* __restrict__ V, unsigned int* __restrict__ T){
  int grp, chunk; map_block(blockIdx.x, grp, chunk);
  int l = threadIdx.x & 63, w = threadIdx.x >> 6;
  const char* Vb = (const char*)(V + (size_t)grp * (NN * 64));
  unsigned int* Tg = T + (size_t)grp * (NN * 64);
  int loff = l * 4;
  for (int it = 0; it < 4; ++it){
    int n = chunk * 16 + w * 4 + it;
    int e0 = RFL(off[n]);
    int e1 = RFL(off[n + 1]);
    float din = dinv[n];
    unsigned sv = *(const unsigned*)(Vb + (n << 8) + loff);
    union { unsigned u; _Float16 h[2]; } cv; cv.u = sv;
    float ax = din * (float)cv.h[0];
    float ay = din * (float)cv.h[1];
    const int4* c4 = (const int4*)(csr + e0);
    int nq = (e1 - e0) >> 2;
    int4 ca, cb;
    if (nq > 0){ ca = c4[0]; cb = c4[1]; }
    for (int q = 0; q < nq; ++q){
      int4 na, nb;
      if (q + 1 < nq){ na = c4[2*q + 2]; nb = c4[2*q + 3]; }
      edge4(Vb, loff,
            RFL(ca.x), __int_as_float(RFL(ca.y)),
            RFL(ca.z), __int_as_float(RFL(ca.w)),
            RFL(cb.x), __int_as_float(RFL(cb.y)),
            RFL(cb.z), __int_as_float(RFL(cb.w)), ax, ay);
      ca = na; cb = nb;
    }
    unsigned us = (unsigned)f2h(din * ax) | ((unsigned)f2h(din * ay) << 16);
    Tg[((size_t)n << 6) + l] = us;
  }
}

// ---- agg layer 2 + epilogue: out = tanh(A*t1 + srow*bb + b2) fp32 ----------
__global__ __launch_bounds__(256) void k_agg2(const int* __restrict__ off,
    const int2* __restrict__ csr, const float* __restrict__ dinv,
    const float* __restrict__ srow, const float* __restrict__ bb,
    const float* __restrict__ b2, const unsigned int* __restrict__ V,
    float* __restrict__ out){
  int grp, chunk; map_block(blockIdx.x, grp, chunk);
  int l = threadIdx.x & 63, w = threadIdx.x >> 6;
  int p = l >> 4, fi = l & 15;
  const char* Vb = (const char*)(V + (size_t)grp * (NN * 64));
  int pg = grp * PG + p;
  float2 bbq = ((const float2*)bb)[fi];
  float2 b2q = ((const float2*)b2)[fi];
  float* outp = out + (size_t)pg * (NN * FF);
  int loff = l * 4;
  for (int it = 0; it < 4; ++it){
    int n = chunk * 16 + w * 4 + it;
    int e0 = RFL(off[n]);
    int e1 = RFL(off[n + 1]);
    float din = dinv[n];
    unsigned sv = *(const unsigned*)(Vb + (n << 8) + loff);
    union { unsigned u; _Float16 h[2]; } cv; cv.u = sv;
    float ax = din * (float)cv.h[0];
    float ay = din * (float)cv.h[1];
    const int4* c4 = (const int4*)(csr + e0);
    int nq = (e1 - e0) >> 2;
    int4 ca, cb;
    if (nq > 0){ ca = c4[0]; cb = c4[1]; }
    for (int q = 0; q < nq; ++q){
      int4 na, nb;
      if (q + 1 < nq){ na = c4[2*q + 2]; nb = c4[2*q + 3]; }
      edge4(Vb, loff,
            RFL(ca.x), __int_as_float(RFL(ca.y)),
            RFL(ca.z), __int_as_float(RFL(ca.w)),
            RFL(cb.x), __int_as_float(RFL(cb.y)),
            RFL(cb.z), __int_as_float(RFL(cb.w)), ax, ay);
      ca = na; cb = nb;
    }
    float sr = srow[n];
    float2 o;
    o.x = tanhf(din * ax + sr * bbq.x + b2q.x);
    o.y = tanhf(din * ay + sr * bbq.y + b2q.y);
    ((float2*)(outp + (size_t)n * FF))[fi] = o;
  }
}

extern "C" void kernel_launch(void* const* d_in, const int* in_sizes, int n_in,
                              void* d_out, int out_size, void* d_ws, size_t ws_size,
                              hipStream_t stream){
  const float* x    = (const float*)d_in[0];
  const float* mask = (const float*)d_in[1];
  const int*   ei   = (const int*)d_in[2];
  const float* W1   = (const float*)d_in[3];
  const float* b1   = (const float*)d_in[4];
  const float* W2   = (const float*)d_in[5];
  const float* b2   = (const float*)d_in[6];
  float* out = (float*)d_out;
  const int E = in_sizes[2] / 2;   // 320000
  const int CSRCAP = E + 3 * NN + 64;  // padded-to-4 worst case + overread slack

  char* wsp = (char*)d_ws;
  auto alloc = [&](size_t bytes) -> char* {
    char* p = wsp; wsp += (bytes + 255) & ~(size_t)255; return p;
  };
  int*   cnt  = (int*)  alloc((size_t)NN * 4);
  int*   off  = (int*)  alloc((size_t)(NN + 1) * 4);
  int*   cur  = (int*)  alloc((size_t)NN * 4);
  float* dinv = (float*)alloc((size_t)NN * 4);
  float* srow = (float*)alloc((size_t)NN * 4);
  float* W12  = (float*)alloc(33 * 32 * 4);
  float* bbv  = (float*)alloc(32 * 4);
  int2*  csr  = (int2*) alloc((size_t)CSRCAP * 8);
  const size_t per_group = (size_t)NN * 64 * 4;    // [n][4p][32f] fp16 = 2.56MB
  unsigned int* hw = (unsigned int*)alloc((size_t)NGRP * per_group);
  unsigned int* t1 = (unsigned int*)alloc((size_t)NGRP * per_group);

  hipMemsetAsync(cnt, 0, (size_t)NN * 4, stream);
  hipMemsetAsync(cur, 0, (size_t)NN * 4, stream);
  hipMemsetAsync(csr, 0, (size_t)CSRCAP * 8, stream);   // pad entries: row 0, w=0
  k_count  <<<(E + 255) / 256, 256, 0, stream>>>(ei + E, cnt, E);
  k_scan   <<<1, 1024, 0, stream>>>(cnt, off, dinv);
  k_scatter<<<(E + 255) / 256, 256, 0, stream>>>(ei, off, cur, dinv, csr, E);
  k_w12    <<<1, 256, 0, stream>>>(W1, W2, b1, W12, bbv);
  k_srow   <<<(NN + 255) / 256, 256, 0, stream>>>(off, csr, dinv, srow);

  k_gemm1<<<dim3(79, NGRP), 256, 0, stream>>>(x, mask, W12, (ushort4*)hw);
  k_agg1 <<<15000, 256, 0, stream>>>(off, csr, dinv, hw, t1);
  k_agg2 <<<15000, 256, 0, stream>>>(off, csr, dinv, srow, bbv, b2, t1, out);
}

// Round 4
// 611.627 us; speedup vs baseline: 1.3679x; 1.0363x over previous
//
#include <hip/hip_runtime.h>
#include <hip/hip_fp16.h>

#define NN 10000
#define FF 32
#define PG 4      // pairs per group
#define NGRP 24   // 96 pairs / PG

__device__ __forceinline__ unsigned short f2h(float f){
  union { unsigned short s; _Float16 h; } c; c.h = (_Float16)f; return c.s;
}

// ---- CSR build -------------------------------------------------------------
__global__ void k_count(const int* __restrict__ dst, int* __restrict__ cnt, int E){
  int e = blockIdx.x * 256 + threadIdx.x;
  if (e < E) atomicAdd(&cnt[dst[e]], 1);
}

// exclusive scan of PADDED counts (pad to multiple of 4); dinv from real count.
// Also computes W12 = W1@W2 and bb = b1@W2 (fused to save a dispatch).
__global__ __launch_bounds__(1024) void k_scan(const int* __restrict__ cnt,
                                               int* __restrict__ off,
                                               float* __restrict__ dinv,
                                               const float* __restrict__ W1,
                                               const float* __restrict__ W2,
                                               const float* __restrict__ b1,
                                               float* __restrict__ W12,
                                               float* __restrict__ bb){
  __shared__ int wsum[16];
  __shared__ int carry;
  int tid = threadIdx.x, lane = tid & 63, wv = tid >> 6;
  if (tid == 0) carry = 0;
  __syncthreads();
  for (int base = 0; base < NN; base += 1024){
    int i = base + tid;
    int c = (i < NN) ? cnt[i] : 0;
    int v = (c + 3) & ~3;                      // padded degree
    int s = v;
    #pragma unroll
    for (int o = 1; o < 64; o <<= 1){
      int t = __shfl_up(s, o, 64);
      if (lane >= o) s += t;
    }
    if (lane == 63) wsum[wv] = s;
    __syncthreads();
    if (tid == 0){
      int a = carry;
      #pragma unroll
      for (int k = 0; k < 16; ++k){ int t = wsum[k]; wsum[k] = a; a += t; }
      carry = a;
    }
    __syncthreads();
    if (i < NN){
      off[i]  = wsum[wv] + s - v;              // exclusive padded offset
      dinv[i] = rsqrtf((float)(c + 1));        // real degree + self loop
    }
    __syncthreads();
  }
  if (tid == 0) off[NN] = carry;
  // fused W12 / bb
  for (int idx = tid; idx < 33 * 32; idx += 1024){
    int k = idx >> 5, j = idx & 31;
    float s = 0.f;
    for (int m = 0; m < 64; ++m) s += W1[k * 64 + m] * W2[m * 32 + j];
    W12[idx] = s;
  }
  if (tid < 32){
    int j = tid;
    float s = 0.f;
    for (int m = 0; m < 64; ++m) s += b1[m] * W2[m * 32 + j];
    bb[j] = s;
  }
}

// csr entry: {row byte offset (src*256), fp32 weight dinv[src]}
// pad holes (memset 0) read row 0 with weight 0.0 -> harmless.
__global__ void k_scatter(const int* __restrict__ ei, const int* __restrict__ off,
                          int* __restrict__ cur, const float* __restrict__ dinv,
                          int2* __restrict__ csr, int E){
  int e = blockIdx.x * 256 + threadIdx.x;
  if (e >= E) return;
  int s = ei[e], d = ei[E + e];
  int pos = off[d] + atomicAdd(&cur[d], 1);
  csr[pos] = make_int2(s << 8, __float_as_int(dinv[s]));
}

// ---- s[n] = rowsum(A) ------------------------------------------------------
__global__ void k_srow(const int* __restrict__ off, const int2* __restrict__ csr,
                       const float* __restrict__ dinv, float* __restrict__ srow){
  int n = blockIdx.x * 256 + threadIdx.x;
  if (n >= NN) return;
  float a = dinv[n];
  int e0 = off[n], e1 = off[n + 1];
  for (int j = e0; j < e1; ++j) a += __int_as_float(csr[j].y);  // pads add 0
  srow[n] = dinv[n] * a;
}

// ---- GEMM1: hw[g][n][p=4][f=32] fp16 = x@W12[:32] + mask*W12[32] -----------
// thread: q = feature pair (16), p = pair (4), nl = node lane (4). float2 out.
__global__ __launch_bounds__(256) void k_gemm1(const float* __restrict__ x,
    const float* __restrict__ mask, const float* __restrict__ W12,
    unsigned* __restrict__ hw){
  int t = threadIdx.x;
  int q = t & 15, p = (t >> 4) & 3, nl = t >> 6;
  int grp = blockIdx.y;
  int pg = grp * PG + p;
  const float2* wp = (const float2*)W12;
  float2 wr[33];
  #pragma unroll
  for (int k = 0; k < 33; ++k) wr[k] = wp[k * 16 + q];
  float mv = mask[pg];
  float2 mterm = make_float2(mv * wr[32].x, mv * wr[32].y);
  const float* xbase = x + (size_t)pg * NN * FF;
  unsigned* hwg = hw + (size_t)grp * (NN * 64);
  int n = blockIdx.x * 128 + nl;
  float4 xr[8];
  if (n < NN){
    const float4* xp = (const float4*)(xbase + (size_t)n * FF);
    #pragma unroll
    for (int i = 0; i < 8; ++i) xr[i] = xp[i];
  }
  for (int it = 0; it < 32; ++it){
    int nn = blockIdx.x * 128 + (it + 1) * 4 + nl;
    float4 xn[8];
    if (it < 31 && nn < NN){
      const float4* xp2 = (const float4*)(xbase + (size_t)nn * FF);
      #pragma unroll
      for (int i = 0; i < 8; ++i) xn[i] = xp2[i];
    }
    if (n < NN){
      float2 acc = mterm;
      #pragma unroll
      for (int i = 0; i < 8; ++i){
        float4 v = xr[i];
        int k = 4 * i;
        acc.x += v.x*wr[k].x + v.y*wr[k+1].x + v.z*wr[k+2].x + v.w*wr[k+3].x;
        acc.y += v.x*wr[k].y + v.y*wr[k+1].y + v.z*wr[k+2].y + v.w*wr[k+3].y;
      }
      hwg[(size_t)n * 64 + (p << 4) + q] =
          (unsigned)f2h(acc.x) | ((unsigned)f2h(acc.y) << 16);
    }
    #pragma unroll
    for (int i = 0; i < 8; ++i) xr[i] = xn[i];
    n = nn;
  }
}

// ---- block->group mapping: pin each group to one XCD (blockIdx%8) ----------
__device__ __forceinline__ void map_block(int bx, int& grp, int& chunk){
  int r  = bx / 5000;       // 0..2
  int w8 = bx % 5000;
  grp   = r * 8 + (w8 & 7);
  chunk = w8 >> 3;          // 0..624
}

// 2-deep pipelined edge accumulation: csr q+2 loading, gathers q+1 in flight,
// fma on quad q. Clamped indices instead of branches (dup loads are L1-hot).
__device__ __forceinline__ void agg_edges(int e0, int e1,
    const int2* __restrict__ csr, const char* __restrict__ Vb, int loff,
    float& ax, float& ay){
  int nq = (e1 - e0) >> 2;
  if (nq <= 0) return;
  const int4* c4 = (const int4*)(csr + e0);
  int qlast = nq - 1;
  int4 ca0 = c4[0], cb0 = c4[1];
  int i1 = (1 <= qlast) ? 1 : qlast;
  int4 ca1 = c4[2 * i1], cb1 = c4[2 * i1 + 1];
  unsigned r0 = *(const unsigned*)(Vb + ca0.x + loff);
  unsigned r1 = *(const unsigned*)(Vb + ca0.z + loff);
  unsigned r2 = *(const unsigned*)(Vb + cb0.x + loff);
  unsigned r3 = *(const unsigned*)(Vb + cb0.z + loff);
  for (int q = 0; q < nq; ++q){
    unsigned s0 = *(const unsigned*)(Vb + ca1.x + loff);
    unsigned s1 = *(const unsigned*)(Vb + ca1.z + loff);
    unsigned s2 = *(const unsigned*)(Vb + cb1.x + loff);
    unsigned s3 = *(const unsigned*)(Vb + cb1.z + loff);
    int i2 = (q + 2 <= qlast) ? q + 2 : qlast;
    int4 na = c4[2 * i2], nb = c4[2 * i2 + 1];
    float w0 = __int_as_float(ca0.y), w1 = __int_as_float(ca0.w);
    float w2 = __int_as_float(cb0.y), w3 = __int_as_float(cb0.w);
    union { unsigned u; _Float16 h[2]; } u0, u1, u2, u3;
    u0.u = r0; u1.u = r1; u2.u = r2; u3.u = r3;
    ax += w0*(float)u0.h[0] + w1*(float)u1.h[0] + w2*(float)u2.h[0] + w3*(float)u3.h[0];
    ay += w0*(float)u0.h[1] + w1*(float)u1.h[1] + w2*(float)u2.h[1] + w3*(float)u3.h[1];
    ca0 = ca1; cb0 = cb1; ca1 = na; cb1 = nb;
    r0 = s0; r1 = s1; r2 = s2; r3 = s3;
  }
}

// ---- agg layer 1: t1 = A*hw (fp16 rows, fp32 accum) ------------------------
__global__ __launch_bounds__(256) void k_agg1(const int* __restrict__ off,
    const int2* __restrict__ csr, const float* __restrict__ dinv,
    const unsigned int* __restrict__ V, unsigned int* __restrict__ T){
  int grp, chunk; map_block(blockIdx.x, grp, chunk);
  int tid = threadIdx.x;
  int l = tid & 63;
  int wv = __builtin_amdgcn_readfirstlane(tid) >> 6;   // wave-uniform
  const char* Vb = (const char*)(V + (size_t)grp * (NN * 64));
  unsigned int* Tg = T + (size_t)grp * (NN * 64);
  int loff = l * 4;
  for (int it = 0; it < 4; ++it){
    int n = chunk * 16 + wv * 4 + it;
    float din = dinv[n];
    int e0 = off[n], e1 = off[n + 1];
    unsigned sv = *(const unsigned*)(Vb + (n << 8) + loff);
    union { unsigned u; _Float16 h[2]; } cv; cv.u = sv;
    float ax = din * (float)cv.h[0];
    float ay = din * (float)cv.h[1];
    agg_edges(e0, e1, csr, Vb, loff, ax, ay);
    Tg[((size_t)n << 6) + l] =
        (unsigned)f2h(din * ax) | ((unsigned)f2h(din * ay) << 16);
  }
}

// ---- agg layer 2 + epilogue: out = tanh(A*t1 + srow*bb + b2) fp32 ----------
__global__ __launch_bounds__(256) void k_agg2(const int* __restrict__ off,
    const int2* __restrict__ csr, const float* __restrict__ dinv,
    const float* __restrict__ srow, const float* __restrict__ bb,
    const float* __restrict__ b2, const unsigned int* __restrict__ V,
    float* __restrict__ out){
  int grp, chunk; map_block(blockIdx.x, grp, chunk);
  int tid = threadIdx.x;
  int l = tid & 63;
  int wv = __builtin_amdgcn_readfirstlane(tid) >> 6;
  int p = l >> 4, fi = l & 15;
  const char* Vb = (const char*)(V + (size_t)grp * (NN * 64));
  int pg = grp * PG + p;
  float2 bbq = ((const float2*)bb)[fi];
  float2 b2q = ((const float2*)b2)[fi];
  float* outp = out + (size_t)pg * (NN * FF);
  int loff = l * 4;
  for (int it = 0; it < 4; ++it){
    int n = chunk * 16 + wv * 4 + it;
    float din = dinv[n];
    int e0 = off[n], e1 = off[n + 1];
    unsigned sv = *(const unsigned*)(Vb + (n << 8) + loff);
    union { unsigned u; _Float16 h[2]; } cv; cv.u = sv;
    float ax = din * (float)cv.h[0];
    float ay = din * (float)cv.h[1];
    agg_edges(e0, e1, csr, Vb, loff, ax, ay);
    float sr = srow[n];
    float2 o;
    o.x = tanhf(din * ax + sr * bbq.x + b2q.x);
    o.y = tanhf(din * ay + sr * bbq.y + b2q.y);
    ((float2*)(outp + (size_t)n * FF))[fi] = o;
  }
}

extern "C" void kernel_launch(void* const* d_in, const int* in_sizes, int n_in,
                              void* d_out, int out_size, void* d_ws, size_t ws_size,
                              hipStream_t stream){
  const float* x    = (const float*)d_in[0];
  const float* mask = (const float*)d_in[1];
  const int*   ei   = (const int*)d_in[2];
  const float* W1   = (const float*)d_in[3];
  const float* b1   = (const float*)d_in[4];
  const float* W2   = (const float*)d_in[5];
  const float* b2   = (const float*)d_in[6];
  float* out = (float*)d_out;
  const int E = in_sizes[2] / 2;   // 320000
  const int CSRCAP = E + 3 * NN + 64;  // padded-to-4 worst case + overread slack

  char* wsp = (char*)d_ws;
  auto alloc = [&](size_t bytes) -> char* {
    char* p = wsp; wsp += (bytes + 255) & ~(size_t)255; return p;
  };
  int*   cnt  = (int*)  alloc((size_t)NN * 4);
  int*   off  = (int*)  alloc((size_t)(NN + 1) * 4);
  int*   cur  = (int*)  alloc((size_t)NN * 4);
  float* dinv = (float*)alloc((size_t)NN * 4);
  float* srow = (float*)alloc((size_t)NN * 4);
  float* W12  = (float*)alloc(33 * 32 * 4);
  float* bbv  = (float*)alloc(32 * 4);
  int2*  csr  = (int2*) alloc((size_t)CSRCAP * 8);
  const size_t per_group = (size_t)NN * 64 * 4;    // [n][4p][32f] fp16 = 2.56MB
  unsigned int* hw = (unsigned int*)alloc((size_t)NGRP * per_group);
  unsigned int* t1 = (unsigned int*)alloc((size_t)NGRP * per_group);

  hipMemsetAsync(cnt, 0, (size_t)NN * 4, stream);
  hipMemsetAsync(cur, 0, (size_t)NN * 4, stream);
  hipMemsetAsync(csr, 0, (size_t)CSRCAP * 8, stream);   // pad entries: row 0, w=0
  k_count  <<<(E + 255) / 256, 256, 0, stream>>>(ei + E, cnt, E);
  k_scan   <<<1, 1024, 0, stream>>>(cnt, off, dinv, W1, W2, b1, W12, bbv);
  k_scatter<<<(E + 255) / 256, 256, 0, stream>>>(ei, off, cur, dinv, csr, E);
  k_srow   <<<(NN + 255) / 256, 256, 0, stream>>>(off, csr, dinv, srow);

  k_gemm1<<<dim3(79, NGRP), 256, 0, stream>>>(x, mask, W12, hw);
  k_agg1 <<<15000, 256, 0, stream>>>(off, csr, dinv, hw, t1);
  k_agg2 <<<15000, 256, 0, stream>>>(off, csr, dinv, srow, bbv, b2, t1, out);
}